// Round 1
// baseline (703.731 us; speedup 1.0000x reference)
//
#include <hip/hip_runtime.h>
#include <math.h>

#define NTOK 16384
#define DDIM 2048
#define NEXP 64
#define KC   64
#define NCHUNK (DDIM / KC)

// Pack both weight matrices transposed: WT[k*128 + e], e<64 -> W_topk, e>=64 -> W_noise
__global__ __launch_bounds__(256) void pack_w(const float* __restrict__ Wt,
                                              const float* __restrict__ Wn,
                                              float* __restrict__ WT) {
    int t = blockIdx.x * 256 + threadIdx.x;   // 0 .. 2048*128-1
    int k = t >> 7;
    int e = t & 127;
    float v = (e < NEXP) ? Wt[(size_t)e * DDIM + k]
                         : Wn[(size_t)(e - NEXP) * DDIM + k];
    WT[t] = v;
}

__global__ __launch_bounds__(256) void router_main(const float* __restrict__ x,
                                                   const float* __restrict__ WT,
                                                   const float* __restrict__ noise,
                                                   float* __restrict__ out) {
    // smem partition: xs[KC*65] (x chunk, [k][token] pad 65), ws[KC*128] (W chunk)
    __shared__ float smem[KC * 65 + KC * 128];   // 12352 floats = 49.4 KB
    float* xs = smem;
    float* ws = smem + KC * 65;

    const int tid  = threadIdx.x;
    const int lane = tid & 63;          // token within block (compute phase)
    const int wv   = tid >> 6;          // wave 0..3
    const int tok0 = blockIdx.x * 64;
    const int e0   = wv * 32;           // this wave's 32 outputs (of 128)

    float acc[32];
#pragma unroll
    for (int i = 0; i < 32; ++i) acc[i] = 0.f;

    // staging map: thread -> (token, k-group of 16)
    const int stok = tid >> 2;
    const int skg  = tid & 3;
    const float* xrow = x + (size_t)(tok0 + stok) * DDIM + skg * 16;

    float4 xr[4];
    float4 wr[8];

    // ---- prologue: stage chunk 0 ----
    {
        const float* wp = WT + (size_t)tid * 4;
#pragma unroll
        for (int j = 0; j < 4; ++j) xr[j] = *(const float4*)(xrow + j * 4);
#pragma unroll
        for (int i = 0; i < 8; ++i) wr[i] = *(const float4*)(wp + i * 1024);
#pragma unroll
        for (int j = 0; j < 4; ++j) {
            xs[(skg*16 + j*4 + 0)*65 + stok] = xr[j].x;
            xs[(skg*16 + j*4 + 1)*65 + stok] = xr[j].y;
            xs[(skg*16 + j*4 + 2)*65 + stok] = xr[j].z;
            xs[(skg*16 + j*4 + 3)*65 + stok] = xr[j].w;
        }
#pragma unroll
        for (int i = 0; i < 8; ++i) *(float4*)(ws + tid*4 + i*1024) = wr[i];
    }
    __syncthreads();

    // ---- main K loop ----
    for (int c = 0; c < NCHUNK; ++c) {
        if (c + 1 < NCHUNK) {   // prefetch next chunk into registers
            const float* wp = WT + (size_t)(c + 1) * (KC * 128) + tid * 4;
#pragma unroll
            for (int j = 0; j < 4; ++j) xr[j] = *(const float4*)(xrow + (c+1)*KC + j*4);
#pragma unroll
            for (int i = 0; i < 8; ++i) wr[i] = *(const float4*)(wp + i * 1024);
        }
#pragma unroll 4
        for (int k = 0; k < KC; ++k) {
            float xv = xs[k*65 + lane];                 // per-lane, conflict-free
            const float* wp2 = ws + k*128 + e0;         // wave-uniform -> broadcast
#pragma unroll
            for (int i = 0; i < 8; ++i) {
                float4 w = *(const float4*)(wp2 + i*4);
                acc[i*4+0] = fmaf(w.x, xv, acc[i*4+0]);
                acc[i*4+1] = fmaf(w.y, xv, acc[i*4+1]);
                acc[i*4+2] = fmaf(w.z, xv, acc[i*4+2]);
                acc[i*4+3] = fmaf(w.w, xv, acc[i*4+3]);
            }
        }
        __syncthreads();
        if (c + 1 < NCHUNK) {
#pragma unroll
            for (int j = 0; j < 4; ++j) {
                xs[(skg*16 + j*4 + 0)*65 + stok] = xr[j].x;
                xs[(skg*16 + j*4 + 1)*65 + stok] = xr[j].y;
                xs[(skg*16 + j*4 + 2)*65 + stok] = xr[j].z;
                xs[(skg*16 + j*4 + 3)*65 + stok] = xr[j].w;
            }
#pragma unroll
            for (int i = 0; i < 8; ++i) *(float4*)(ws + tid*4 + i*1024) = wr[i];
            __syncthreads();
        }
    }

    // ---- epilogue ----
    // logits to LDS: ls[o*65 + token], o in [0,128)
    float*  ls  = smem;                            // 128*65 = 8320 floats
    float4* pt  = (float4*)(smem + 8320);          // partial top2: [4][64]
    float4* fin = (float4*)(smem + 8320 + 1024);   // final per-token

#pragma unroll
    for (int i = 0; i < 32; ++i) ls[(e0 + i)*65 + lane] = acc[i];
    __syncthreads();

    // partial top-2: thread (token = tid&63, expert group eg = tid>>6 covers 16 experts)
    {
        const int ptok = tid & 63;
        const int eg   = tid >> 6;
        float v1 = -INFINITY, v2 = -INFINITY;
        int i1 = 0, i2 = 0;
        const float* nzp = noise + (size_t)(tok0 + ptok) * NEXP + eg * 16;
#pragma unroll
        for (int j4 = 0; j4 < 4; ++j4) {
            float4 nz = *(const float4*)(nzp + j4 * 4);
            float nzv[4] = {nz.x, nz.y, nz.z, nz.w};
#pragma unroll
            for (int cc = 0; cc < 4; ++cc) {
                int e = eg*16 + j4*4 + cc;
                float lg = ls[e*65 + ptok];
                float nl = ls[(NEXP + e)*65 + ptok];
                float soft = log1pf(expf(fminf(nl, 20.f)));
                float cmb  = ((nl > 20.f) ? nl : soft) * nzv[cc] + lg;
                if (cmb > v1)      { v2 = v1; i2 = i1; v1 = cmb; i1 = e; }
                else if (cmb > v2) { v2 = cmb; i2 = e; }
            }
        }
        pt[eg*64 + ptok] = make_float4(v1, (float)i1, v2, (float)i2);
    }
    __syncthreads();

    // merge 4 partials per token (ascending group order keeps jax tie-break: lowest index wins)
    if (tid < 64) {
        float4 g = pt[tid];
        float v1 = g.x, v2 = g.z;
        int i1 = (int)g.y, i2 = (int)g.w;
#pragma unroll
        for (int gg = 1; gg < 4; ++gg) {
            float4 p = pt[gg*64 + tid];
            if (p.x > v1)      { v2 = v1; i2 = i1; v1 = p.x; i1 = (int)p.y; }
            else if (p.x > v2) { v2 = p.x; i2 = (int)p.y; }
            if (p.z > v1)      { v2 = v1; i2 = i1; v1 = p.z; i1 = (int)p.w; }
            else if (p.z > v2) { v2 = p.z; i2 = (int)p.w; }
        }
        float e2  = expf(v2 - v1);
        float inv = 1.f / (1.f + e2);
        fin[tid] = make_float4((float)i1, (float)i2, inv, e2 * inv);
    }
    __syncthreads();

    // probs: block's region is 64*64 contiguous floats; thread writes one float4 (coalesced)
    {
        float4 f = fin[tid >> 4];
        int i1 = (int)f.x, i2 = (int)f.y;
        int eb = (tid & 15) * 4;
        float o[4];
#pragma unroll
        for (int cc = 0; cc < 4; ++cc) {
            int e = eb + cc;
            o[cc] = (e == i1) ? f.z : ((e == i2) ? f.w : 0.f);
        }
        *(float4*)(out + (size_t)tok0 * NEXP + tid * 4) = make_float4(o[0], o[1], o[2], o[3]);
    }
    // indices (as float), after the probs region
    if (tid < 64) {
        float4 f = fin[tid];
        *(float2*)(out + (size_t)NTOK * NEXP + (size_t)(tok0 + tid) * 2) = make_float2(f.x, f.y);
    }
}

extern "C" void kernel_launch(void* const* d_in, const int* in_sizes, int n_in,
                              void* d_out, int out_size, void* d_ws, size_t ws_size,
                              hipStream_t stream) {
    const float* x  = (const float*)d_in[0];
    const float* Wt = (const float*)d_in[1];
    const float* Wn = (const float*)d_in[2];
    const float* nz = (const float*)d_in[3];
    float* out = (float*)d_out;
    float* WT  = (float*)d_ws;   // 2048*128 floats = 1 MB scratch

    hipLaunchKernelGGL(pack_w, dim3((DDIM * 128) / 256), dim3(256), 0, stream, Wt, Wn, WT);
    hipLaunchKernelGGL(router_main, dim3(NTOK / 64), dim3(256), 0, stream, x, WT, nz, out);
}

// Round 2
// 387.411 us; speedup vs baseline: 1.8165x; 1.8165x over previous
//
#include <hip/hip_runtime.h>
#include <math.h>

#define NTOK 16384
#define DDIM 2048
#define NEXP 64
#define KC   64
#define NCHUNK (DDIM / KC)

// Pack W into per-wave-contiguous layout: W3[eg][k][ei] where e = eg*16+ei,
// e<64 -> W_topk row e, e>=64 -> W_noise row e-64. Each wave streams 64B per k.
__global__ __launch_bounds__(256) void pack_w(const float* __restrict__ Wt,
                                              const float* __restrict__ Wn,
                                              float* __restrict__ W3) {
    int t = blockIdx.x * 256 + threadIdx.x;   // 0 .. 128*2048-1
    int eg = t >> 15;                         // /(2048*16): 0..7
    int k  = (t >> 4) & (DDIM - 1);
    int ei = t & 15;
    int e  = eg * 16 + ei;
    float v = (e < NEXP) ? Wt[(size_t)e * DDIM + k]
                         : Wn[(size_t)(e - NEXP) * DDIM + k];
    W3[t] = v;
}

__global__ __launch_bounds__(512) void router_main(const float* __restrict__ x,
                                                   const float* __restrict__ W3,
                                                   const float* __restrict__ noise,
                                                   float* __restrict__ out) {
    // smem: staging = 2 x [64 tok][65] = 8320 floats; epilogue reuses as
    // ls[128*65]=8320 + pt[512 float4]=2048 + fin[64 float4]=256 -> 10624 floats
    __shared__ float smem[10624];
    const int tid  = threadIdx.x;
    const int lane = tid & 63;
    const int wv   = __builtin_amdgcn_readfirstlane(tid >> 6);  // wave 0..7, provably uniform
    const int tok0 = blockIdx.x * 64;

    float* xs0 = smem;           // x chunk, [tok][k] pad 65
    float* xs1 = smem + 4160;

    float acc[16];
#pragma unroll
    for (int i = 0; i < 16; ++i) acc[i] = 0.f;

    // wave's W stream: contiguous [k][16] for its 16 experts -> scalar loads
    const float* wp = W3 + (size_t)wv * (DDIM * 16);

    // staging map: thread -> (token = tid>>3, 8-float k-segment = tid&7)
    const int stok = tid >> 3;
    const int skg  = tid & 7;
    const float* xrow = x + (size_t)(tok0 + stok) * DDIM + skg * 8;
    float* xsw0 = xs0 + stok * 65 + skg * 8;
    float* xsw1 = xs1 + stok * 65 + skg * 8;

    float4 xa, xb;
    // prologue: stage chunk 0
    xa = *(const float4*)(xrow);
    xb = *(const float4*)(xrow + 4);
    *(float4*)(xsw0)     = xa;
    *(float4*)(xsw0 + 4) = xb;
    __syncthreads();

    for (int c = 0; c < NCHUNK; ++c) {
        const float* xs = (c & 1) ? xs1 : xs0;
        float*       xn = (c & 1) ? xsw0 : xsw1;   // write ptr for next chunk
        if (c + 1 < NCHUNK) {                      // prefetch next chunk into regs
            xa = *(const float4*)(xrow + (c + 1) * KC);
            xb = *(const float4*)(xrow + (c + 1) * KC + 4);
        }
        const float* wk = wp + (size_t)c * (KC * 16);
        const float* xl = xs + lane * 65;
#pragma unroll 2
        for (int k4 = 0; k4 < KC; k4 += 4) {
            float4 xv = *(const float4*)(xl + k4);     // 4 k's per ds_read_b128
            float xvk[4] = {xv.x, xv.y, xv.z, xv.w};
#pragma unroll
            for (int kk = 0; kk < 4; ++kk) {
                const float* wkk = wk + (k4 + kk) * 16;  // wave-uniform -> s_load
                float4 w0 = *(const float4*)(wkk);
                float4 w1 = *(const float4*)(wkk + 4);
                float4 w2 = *(const float4*)(wkk + 8);
                float4 w3 = *(const float4*)(wkk + 12);
                float xvv = xvk[kk];
                acc[0]  = fmaf(w0.x, xvv, acc[0]);
                acc[1]  = fmaf(w0.y, xvv, acc[1]);
                acc[2]  = fmaf(w0.z, xvv, acc[2]);
                acc[3]  = fmaf(w0.w, xvv, acc[3]);
                acc[4]  = fmaf(w1.x, xvv, acc[4]);
                acc[5]  = fmaf(w1.y, xvv, acc[5]);
                acc[6]  = fmaf(w1.z, xvv, acc[6]);
                acc[7]  = fmaf(w1.w, xvv, acc[7]);
                acc[8]  = fmaf(w2.x, xvv, acc[8]);
                acc[9]  = fmaf(w2.y, xvv, acc[9]);
                acc[10] = fmaf(w2.z, xvv, acc[10]);
                acc[11] = fmaf(w2.w, xvv, acc[11]);
                acc[12] = fmaf(w3.x, xvv, acc[12]);
                acc[13] = fmaf(w3.y, xvv, acc[13]);
                acc[14] = fmaf(w3.z, xvv, acc[14]);
                acc[15] = fmaf(w3.w, xvv, acc[15]);
            }
        }
        if (c + 1 < NCHUNK) {                      // write next chunk (other buffer)
            *(float4*)(xn)     = xa;
            *(float4*)(xn + 4) = xb;
        }
        __syncthreads();   // one barrier per chunk: protects buffer reuse at c+2
    }

    // ---- epilogue ----
    float*  ls  = smem;                              // [128 experts][65] logits
    float4* pt  = (float4*)(smem + 8320);            // partial top2 [8][64]
    float4* fin = (float4*)(smem + 8320 + 2048);     // per-token final

#pragma unroll
    for (int i = 0; i < 16; ++i) ls[(wv * 16 + i) * 65 + lane] = acc[i];
    __syncthreads();

    // partial top-2: token = tid&63, expert group eg = tid>>6 covers 8 experts (ascending)
    {
        const int ptok = tid & 63;
        const int eg   = tid >> 6;
        float v1 = -INFINITY, v2 = -INFINITY;
        int i1 = 0, i2 = 0;
        const float* nzp = noise + (size_t)(tok0 + ptok) * NEXP + eg * 8;
        float4 nza = *(const float4*)(nzp);
        float4 nzb = *(const float4*)(nzp + 4);
        float nzv[8] = {nza.x, nza.y, nza.z, nza.w, nzb.x, nzb.y, nzb.z, nzb.w};
#pragma unroll
        for (int cc = 0; cc < 8; ++cc) {
            int e = eg * 8 + cc;
            float lg = ls[e * 65 + ptok];
            float nl = ls[(NEXP + e) * 65 + ptok];
            float soft = log1pf(expf(fminf(nl, 20.f)));
            float cmb  = ((nl > 20.f) ? nl : soft) * nzv[cc] + lg;
            if (cmb > v1)      { v2 = v1; i2 = i1; v1 = cmb; i1 = e; }
            else if (cmb > v2) { v2 = cmb; i2 = e; }
        }
        pt[eg * 64 + ptok] = make_float4(v1, (float)i1, v2, (float)i2);
    }
    __syncthreads();

    // merge 8 partials per token (ascending order keeps jax tie-break: lowest index wins)
    if (tid < 64) {
        float4 g = pt[tid];
        float v1 = g.x, v2 = g.z;
        int i1 = (int)g.y, i2 = (int)g.w;
#pragma unroll
        for (int gg = 1; gg < 8; ++gg) {
            float4 p = pt[gg * 64 + tid];
            if (p.x > v1)      { v2 = v1; i2 = i1; v1 = p.x; i1 = (int)p.y; }
            else if (p.x > v2) { v2 = p.x; i2 = (int)p.y; }
            if (p.z > v1)      { v2 = v1; i2 = i1; v1 = p.z; i1 = (int)p.w; }
            else if (p.z > v2) { v2 = p.z; i2 = (int)p.w; }
        }
        float e2  = expf(v2 - v1);
        float inv = 1.f / (1.f + e2);
        fin[tid] = make_float4((float)i1, (float)i2, inv, e2 * inv);
    }
    __syncthreads();

    // probs: all 64 tokens x 64 experts. thread -> token tid>>3, 8-expert segment tid&7
    {
        const int tok = tid >> 3;
        const int seg = tid & 7;
        float4 f = fin[tok];
        int i1 = (int)f.x, i2 = (int)f.y;
        float o[8];
#pragma unroll
        for (int cc = 0; cc < 8; ++cc) {
            int e = seg * 8 + cc;
            o[cc] = (e == i1) ? f.z : ((e == i2) ? f.w : 0.f);
        }
        float* op = out + (size_t)tok0 * NEXP + tok * NEXP + seg * 8;
        *(float4*)(op)     = make_float4(o[0], o[1], o[2], o[3]);
        *(float4*)(op + 4) = make_float4(o[4], o[5], o[6], o[7]);
    }
    // indices (as float) after the probs region
    if (tid < 64) {
        float4 f = fin[tid];
        *(float2*)(out + (size_t)NTOK * NEXP + (size_t)(tok0 + tid) * 2) = make_float2(f.x, f.y);
    }
}

extern "C" void kernel_launch(void* const* d_in, const int* in_sizes, int n_in,
                              void* d_out, int out_size, void* d_ws, size_t ws_size,
                              hipStream_t stream) {
    const float* x  = (const float*)d_in[0];
    const float* Wt = (const float*)d_in[1];
    const float* Wn = (const float*)d_in[2];
    const float* nz = (const float*)d_in[3];
    float* out = (float*)d_out;
    float* W3  = (float*)d_ws;   // 2048*128 floats = 1 MB scratch

    hipLaunchKernelGGL(pack_w, dim3((DDIM * 128) / 256), dim3(256), 0, stream, Wt, Wn, W3);
    hipLaunchKernelGGL(router_main, dim3(NTOK / 64), dim3(512), 0, stream, x, W3, nz, out);
}

// Round 4
// 256.323 us; speedup vs baseline: 2.7455x; 1.5114x over previous
//
#include <hip/hip_runtime.h>
#include <math.h>

#define NTOK 16384
#define DDIM 2048
#define NEXP 64
#define KC   128                 // k per staged chunk
#define NCH  (DDIM / KC)         // 16
#define NKS  (KC / 32)           // 4 ksteps per chunk
#define ROWB 272                 // bytes per LDS row: 128 halfs * 2B + 16B pad
#define PLANE (64 * ROWB)        // 17408 B per split-plane
#define HPLANE 262144            // halfs per W split plane (8*64*64*8)
#define SCALE 4096.0f
#define UNSCALE (1.0f / (SCALE * SCALE))

typedef _Float16 half8 __attribute__((ext_vector_type(8)));
typedef float    f32x4 __attribute__((ext_vector_type(4)));

// Pack W into B-fragment-linear fp16 splits, scaled by 2^12.
// Fragment: tile n (16 experts), kstep ks (k=32), lane l:
//   expert e = n*16 + (l&15), k = ks*32 + (l>>4)*8 + j, j=0..7
// half offset = ((n*64 + ks)*64 + l)*8 + j ; h1 plane at +HPLANE
__global__ __launch_bounds__(256) void pack_w(const float* __restrict__ Wt,
                                              const float* __restrict__ Wn,
                                              _Float16* __restrict__ WB) {
    int t  = blockIdx.x * 256 + threadIdx.x;   // 0 .. 32767
    int n  = t >> 12;
    int ks = (t >> 6) & 63;
    int l  = t & 63;
    int e  = n * 16 + (l & 15);
    int k  = ks * 32 + ((l >> 4) * 8);
    const float* src = ((e < NEXP) ? (Wt + (size_t)e * DDIM)
                                   : (Wn + (size_t)(e - NEXP) * DDIM)) + k;
    half8 h0, h1;
#pragma unroll
    for (int j = 0; j < 8; ++j) {
        float v = src[j] * SCALE;
        _Float16 a = (_Float16)v;
        h0[j] = a;
        h1[j] = (_Float16)(v - (float)a);
    }
    size_t base = (size_t)t * 8;
    *(half8*)(WB + base)          = h0;
    *(half8*)(WB + HPLANE + base) = h1;
}

__global__ __launch_bounds__(512) void router_main(const float* __restrict__ x,
                                                   const _Float16* __restrict__ WB,
                                                   const float* __restrict__ noise,
                                                   float* __restrict__ out) {
    // LDS: 2 chunk-buffers x 2 split-planes x [64 tok][128 halfs + pad]
    __shared__ char smem[2 * 2 * PLANE];    // 69632 B
    const int tid  = threadIdx.x;
    const int lane = tid & 63;
    const int wv   = tid >> 6;      // 0..7
    const int q    = wv & 3;        // token quarter (16 tokens)
    const int eh   = wv >> 2;       // expert half: 0 -> W_topk, 1 -> W_noise
    const int tok0 = blockIdx.x * 64;

    // staging map: thread -> (token = tid>>3, 16-float k-segment = tid&7)
    const int stok = tid >> 3;
    const int skg  = tid & 7;
    const float* xrow = x + (size_t)(tok0 + stok) * DDIM + skg * 16;
    const int woff = stok * ROWB + skg * 32;   // byte offset within a plane

    f32x4 acc[4];
#pragma unroll
    for (int t = 0; t < 4; ++t) acc[t] = (f32x4){0.f, 0.f, 0.f, 0.f};

    float4 xr[4];

#define LOADX(c)                                                        \
    {                                                                   \
        const float* xb = xrow + (c) * KC;                              \
        xr[0] = *(const float4*)(xb);                                   \
        xr[1] = *(const float4*)(xb + 4);                               \
        xr[2] = *(const float4*)(xb + 8);                               \
        xr[3] = *(const float4*)(xb + 12);                              \
    }

#define STAGE(bi)                                                       \
    {                                                                   \
        char* p = smem + (bi) * (2 * PLANE) + woff;                     \
        half8 A0, A1, B0, B1;                                           \
        float v[16] = {xr[0].x, xr[0].y, xr[0].z, xr[0].w,              \
                       xr[1].x, xr[1].y, xr[1].z, xr[1].w,              \
                       xr[2].x, xr[2].y, xr[2].z, xr[2].w,              \
                       xr[3].x, xr[3].y, xr[3].z, xr[3].w};             \
        _Float16 lo[16], hi[16];                                        \
        _Pragma("unroll")                                               \
        for (int m = 0; m < 16; ++m) {                                  \
            float s = v[m] * SCALE;                                     \
            _Float16 a = (_Float16)s;                                   \
            lo[m] = a;                                                  \
            hi[m] = (_Float16)(s - (float)a);                           \
        }                                                               \
        _Pragma("unroll")                                               \
        for (int m = 0; m < 8; ++m) {                                   \
            A0[m] = lo[m];     A1[m] = lo[8 + m];                       \
            B0[m] = hi[m];     B1[m] = hi[8 + m];                       \
        }                                                               \
        *(half8*)(p)              = A0;                                 \
        *(half8*)(p + 16)         = A1;                                 \
        *(half8*)(p + PLANE)      = B0;                                 \
        *(half8*)(p + PLANE + 16) = B1;                                 \
    }

    // prologue: stage chunk 0, issue chunk 1 loads
    LOADX(0);
    STAGE(0);
    LOADX(1);
    __syncthreads();

    const char* arow0 = smem + (q * 16 + (lane & 15)) * ROWB + ((lane >> 4) * 16);

    for (int c = 0; c < NCH; ++c) {
        const char* arow = arow0 + (c & 1) * (2 * PLANE);
#pragma unroll
        for (int ks = 0; ks < NKS; ++ks) {
            half8 a0 = *(const half8*)(arow + ks * 64);
            half8 a1 = *(const half8*)(arow + ks * 64 + PLANE);
            int gks = c * NKS + ks;
            const _Float16* bb = WB + (((size_t)(eh * 4) * 64 + gks) * 64 + lane) * 8;
#pragma unroll
            for (int t = 0; t < 4; ++t) {
                half8 b0 = *(const half8*)(bb);
                half8 b1 = *(const half8*)(bb + HPLANE);
                acc[t] = __builtin_amdgcn_mfma_f32_16x16x32_f16(a0, b0, acc[t], 0, 0, 0);
                acc[t] = __builtin_amdgcn_mfma_f32_16x16x32_f16(a1, b0, acc[t], 0, 0, 0);
                acc[t] = __builtin_amdgcn_mfma_f32_16x16x32_f16(a0, b1, acc[t], 0, 0, 0);
                bb += 64 * 64 * 8;    // next expert tile
            }
        }
        if (c + 1 < NCH) {
            __syncthreads();          // everyone done reading the buffer we overwrite
            STAGE((c + 1) & 1);
            if (c + 2 < NCH) LOADX(c + 2);
            __syncthreads();          // staged chunk visible before next compute
        }
    }

    // ---- epilogue (round-2 verified structure) ----
    __syncthreads();
    float*  ls  = (float*)smem;                        // [128 experts][65] logits
    float4* pt  = (float4*)((float*)smem + 8320);      // partial top2 [8][64]
    float4* fin = (float4*)((float*)smem + 8320 + 2048);

    // scatter MFMA accumulators: D[tok=(l>>4)*4+r][exp = t*16 + (l&15)]
#pragma unroll
    for (int t = 0; t < 4; ++t) {
        int e  = eh * 64 + t * 16 + (lane & 15);
        int tl = q * 16 + ((lane >> 4) << 2);
#pragma unroll
        for (int r = 0; r < 4; ++r)
            ls[e * 65 + tl + r] = acc[t][r] * UNSCALE;
    }
    __syncthreads();

    // partial top-2: token = tid&63, expert group eg = tid>>6 covers 8 experts (ascending)
    {
        const int ptok = tid & 63;
        const int eg   = tid >> 6;
        float v1 = -INFINITY, v2 = -INFINITY;
        int i1 = 0, i2 = 0;
        const float* nzp = noise + (size_t)(tok0 + ptok) * NEXP + eg * 8;
        float4 nza = *(const float4*)(nzp);
        float4 nzb = *(const float4*)(nzp + 4);
        float nzv[8] = {nza.x, nza.y, nza.z, nza.w, nzb.x, nzb.y, nzb.z, nzb.w};
#pragma unroll
        for (int cc = 0; cc < 8; ++cc) {
            int e = eg * 8 + cc;
            float lg = ls[e * 65 + ptok];
            float nl = ls[(NEXP + e) * 65 + ptok];
            float soft = log1pf(expf(fminf(nl, 20.f)));
            float cmb  = ((nl > 20.f) ? nl : soft) * nzv[cc] + lg;
            if (cmb > v1)      { v2 = v1; i2 = i1; v1 = cmb; i1 = e; }
            else if (cmb > v2) { v2 = cmb; i2 = e; }
        }
        pt[eg * 64 + ptok] = make_float4(v1, (float)i1, v2, (float)i2);
    }
    __syncthreads();

    // merge 8 partials (ascending order keeps jax tie-break: lowest index wins)
    if (tid < 64) {
        float4 g = pt[tid];
        float v1 = g.x, v2 = g.z;
        int i1 = (int)g.y, i2 = (int)g.w;
#pragma unroll
        for (int gg = 1; gg < 8; ++gg) {
            float4 p = pt[gg * 64 + tid];
            if (p.x > v1)      { v2 = v1; i2 = i1; v1 = p.x; i1 = (int)p.y; }
            else if (p.x > v2) { v2 = p.x; i2 = (int)p.y; }
            if (p.z > v1)      { v2 = v1; i2 = i1; v1 = p.z; i1 = (int)p.w; }
            else if (p.z > v2) { v2 = p.z; i2 = (int)p.w; }
        }
        float e2  = expf(v2 - v1);
        float inv = 1.f / (1.f + e2);
        fin[tid] = make_float4((float)i1, (float)i2, inv, e2 * inv);
    }
    __syncthreads();

    // probs: token tid>>3, 8-expert segment tid&7
    {
        const int tok = tid >> 3;
        const int seg = tid & 7;
        float4 f = fin[tok];
        int i1 = (int)f.x, i2 = (int)f.y;
        float o[8];
#pragma unroll
        for (int cc = 0; cc < 8; ++cc) {
            int e = seg * 8 + cc;
            o[cc] = (e == i1) ? f.z : ((e == i2) ? f.w : 0.f);
        }
        float* op = out + (size_t)tok0 * NEXP + tok * NEXP + seg * 8;
        *(float4*)(op)     = make_float4(o[0], o[1], o[2], o[3]);
        *(float4*)(op + 4) = make_float4(o[4], o[5], o[6], o[7]);
    }
    // indices (as float) after the probs region
    if (tid < 64) {
        float4 f = fin[tid];
        *(float2*)(out + (size_t)NTOK * NEXP + (size_t)(tok0 + tid) * 2) = make_float2(f.x, f.y);
    }
#undef LOADX
#undef STAGE
}

extern "C" void kernel_launch(void* const* d_in, const int* in_sizes, int n_in,
                              void* d_out, int out_size, void* d_ws, size_t ws_size,
                              hipStream_t stream) {
    const float* x  = (const float*)d_in[0];
    const float* Wt = (const float*)d_in[1];
    const float* Wn = (const float*)d_in[2];
    const float* nz = (const float*)d_in[3];
    float* out = (float*)d_out;
    _Float16* WB = (_Float16*)d_ws;   // 2 * 262144 halfs = 1 MB scratch

    hipLaunchKernelGGL(pack_w, dim3(128), dim3(256), 0, stream, Wt, Wn, WB);
    hipLaunchKernelGGL(router_main, dim3(NTOK / 64), dim3(512), 0, stream, x, WB, nz, out);
}

// Round 5
// 216.369 us; speedup vs baseline: 3.2525x; 1.1847x over previous
//
#include <hip/hip_runtime.h>
#include <math.h>

#define NTOK 16384
#define DDIM 2048
#define NEXP 64
#define TOKB 32                  // tokens per block
#define KQ   512                 // K per kh-split (DDIM/4)
#define KC   64                  // k per chunk per region
#define NCHUNK 8                 // KQ/KC
#define ROWB 144                 // 64 halfs*2B + 16B pad
#define PLANEB 4608              // 32*ROWB
#define REGS 9232                // 2*PLANEB + 16B bank stagger
#define HPLANE 262144            // halfs per W split plane
#define SCALE 4096.0f
#define UNSCALE (1.0f / (SCALE * SCALE))

typedef _Float16 half8 __attribute__((ext_vector_type(8)));
typedef float    f32x4 __attribute__((ext_vector_type(4)));

// Pack W fragment-linear fp16 2-plane split. Block b handles expert-row b (coalesced reads).
// Fragment: tile n, kstep ks, lane l: e = n*16+(l&15), k = ks*32+(l>>4)*8+j.
__global__ __launch_bounds__(256) void pack_w(const float* __restrict__ Wt,
                                              const float* __restrict__ Wn,
                                              _Float16* __restrict__ WB) {
    int t  = blockIdx.x * 256 + threadIdx.x;   // 0..32767
    int e  = t >> 8;                           // 0..127 (block-major -> coalesced row reads)
    int k8 = t & 255;
    int k  = k8 * 8;
    const float* src = ((e < NEXP) ? (Wt + (size_t)e * DDIM)
                                   : (Wn + (size_t)(e - NEXP) * DDIM)) + k;
    int n = e >> 4, ei = e & 15, ks = k8 >> 2, q = k8 & 3;
    size_t off = (((size_t)n * 64 + ks) * 64 + (q * 16 + ei)) * 8;
    half8 h0, h1;
#pragma unroll
    for (int j = 0; j < 8; ++j) {
        float v = src[j] * SCALE;
        _Float16 a = (_Float16)v;
        h0[j] = a;
        h1[j] = (_Float16)(v - (float)a);
    }
    *(half8*)(WB + off)          = h0;
    *(half8*)(WB + HPLANE + off) = h1;
}

__global__ __launch_bounds__(512, 4) void router_main(const float* __restrict__ x,
                                                      const _Float16* __restrict__ WB,
                                                      const float* __restrict__ noise,
                                                      float* __restrict__ out) {
    // smem: staging = 4 kh-regions x [2 planes][32 tok][144B] (36928 B used)
    //       epilogue reuses as pw[4][128][33] f32 partials = 67584 B
    __shared__ float smem[4 * 128 * 33];
    char* stg = (char*)smem;

    const int tid  = threadIdx.x;
    const int lane = tid & 63;
    const int w    = tid >> 6;        // 0..7
    const int eh   = w & 1;           // expert half (4 tiles)
    const int kh   = w >> 1;          // K quarter (512 k)
    const int tok0 = blockIdx.x * TOKB;

    f32x4 acc[2][4];
#pragma unroll
    for (int tt = 0; tt < 2; ++tt)
#pragma unroll
        for (int t = 0; t < 4; ++t) acc[tt][t] = (f32x4){0.f, 0.f, 0.f, 0.f};

    // staging map: thread -> (token = tid>>4, seg = tid&15); seg -> (kh region, 16-k slice)
    const int stok = tid >> 4;
    const int seg  = tid & 15;
    const int khs  = seg >> 2;
    const int kk   = (seg & 3) * 16;
    const float* xrow = x + (size_t)(tok0 + stok) * DDIM + khs * KQ + kk;
    char* wlo = stg + khs * REGS + stok * ROWB + kk * 2;

    float4 xr[4];

#define LOADX(c)                                                        \
    {                                                                   \
        const float* p = xrow + (c) * KC;                               \
        xr[0] = *(const float4*)(p);                                    \
        xr[1] = *(const float4*)(p + 4);                                \
        xr[2] = *(const float4*)(p + 8);                                \
        xr[3] = *(const float4*)(p + 12);                               \
    }

#define STAGE()                                                         \
    {                                                                   \
        float v[16] = {xr[0].x, xr[0].y, xr[0].z, xr[0].w,              \
                       xr[1].x, xr[1].y, xr[1].z, xr[1].w,              \
                       xr[2].x, xr[2].y, xr[2].z, xr[2].w,              \
                       xr[3].x, xr[3].y, xr[3].z, xr[3].w};             \
        half8 L0, L1, H0, H1;                                           \
        _Pragma("unroll")                                               \
        for (int m = 0; m < 8; ++m) {                                   \
            float s0 = v[m] * SCALE;                                    \
            float s1 = v[8 + m] * SCALE;                                \
            _Float16 a0 = (_Float16)s0, a1 = (_Float16)s1;              \
            L0[m] = a0;  L1[m] = a1;                                    \
            H0[m] = (_Float16)(s0 - (float)a0);                         \
            H1[m] = (_Float16)(s1 - (float)a1);                         \
        }                                                               \
        *(half8*)(wlo)               = L0;                              \
        *(half8*)(wlo + 16)          = L1;                              \
        *(half8*)(wlo + PLANEB)      = H0;                              \
        *(half8*)(wlo + PLANEB + 16) = H1;                              \
    }

    // compute bases
    const char* abase = stg + kh * REGS + (lane & 15) * ROWB + ((lane >> 4) * 16);
    const _Float16* bb = WB + (((size_t)(eh * 4) * 64 + (size_t)kh * 16) * 64 + lane) * 8;

    LOADX(0);
    STAGE();
    __syncthreads();

    for (int c = 0; c < NCHUNK; ++c) {
        if (c + 1 < NCHUNK) LOADX(c + 1);
        const _Float16* bc = bb + (size_t)c * 1024;
#pragma unroll
        for (int ks = 0; ks < 2; ++ks) {
            half8 aL0 = *(const half8*)(abase + ks * 64);                       // tt0 lo
            half8 aH0 = *(const half8*)(abase + ks * 64 + PLANEB);              // tt0 hi
            half8 aL1 = *(const half8*)(abase + 16 * ROWB + ks * 64);           // tt1 lo
            half8 aH1 = *(const half8*)(abase + 16 * ROWB + ks * 64 + PLANEB);  // tt1 hi
#pragma unroll
            for (int t = 0; t < 4; ++t) {
                const _Float16* bp = bc + ks * 512 + (size_t)t * 32768;
                half8 b0 = *(const half8*)(bp);
                half8 b1 = *(const half8*)(bp + HPLANE);
                acc[0][t] = __builtin_amdgcn_mfma_f32_16x16x32_f16(aL0, b0, acc[0][t], 0, 0, 0);
                acc[0][t] = __builtin_amdgcn_mfma_f32_16x16x32_f16(aH0, b0, acc[0][t], 0, 0, 0);
                acc[0][t] = __builtin_amdgcn_mfma_f32_16x16x32_f16(aL0, b1, acc[0][t], 0, 0, 0);
                acc[1][t] = __builtin_amdgcn_mfma_f32_16x16x32_f16(aL1, b0, acc[1][t], 0, 0, 0);
                acc[1][t] = __builtin_amdgcn_mfma_f32_16x16x32_f16(aH1, b0, acc[1][t], 0, 0, 0);
                acc[1][t] = __builtin_amdgcn_mfma_f32_16x16x32_f16(aL1, b1, acc[1][t], 0, 0, 0);
            }
        }
        __syncthreads();           // all reads of chunk c done
        if (c + 1 < NCHUNK) {
            STAGE();               // overwrite with chunk c+1
            __syncthreads();
        }
    }

    // ---- epilogue ----
    // partials: pw[kh][e][33] ; D layout: row tok = (l>>4)*4 + r, col e-part = l&15
    float* pw = smem;
#pragma unroll
    for (int tt = 0; tt < 2; ++tt)
#pragma unroll
        for (int t = 0; t < 4; ++t) {
            int e    = eh * 64 + t * 16 + (lane & 15);
            int tokl = tt * 16 + ((lane >> 4) << 2);
            int base = (kh * 128 + e) * 33 + tokl;
#pragma unroll
            for (int r = 0; r < 4; ++r)
                pw[base + r] = acc[tt][t][r] * UNSCALE;
        }
    __syncthreads();

    // reduce over kh: thread -> (e = tid>>2, 8 tokens)
    {
        int e  = tid >> 2;
        int t0 = (tid & 3) * 8;
#pragma unroll
        for (int j = 0; j < 8; ++j) {
            int tk = t0 + j;
            float s = pw[(0 * 128 + e) * 33 + tk] + pw[(1 * 128 + e) * 33 + tk]
                    + pw[(2 * 128 + e) * 33 + tk] + pw[(3 * 128 + e) * 33 + tk];
            pw[e * 33 + tk] = s;      // lf[e][tok] in kh0 region (unique owner)
        }
    }
    __syncthreads();

    float4* pt  = (float4*)(smem + 4224);          // [16][32] partial top2
    float4* fin = (float4*)(smem + 4224 + 2048);   // [32] per-token final

    // partial top-2: tok = tid&31, eg = tid>>5 covers 4 experts (ascending)
    {
        const int ptok = tid & 31;
        const int eg   = tid >> 5;
        float v1 = -INFINITY, v2 = -INFINITY;
        int i1 = 0, i2 = 0;
        float4 nz = *(const float4*)(noise + (size_t)(tok0 + ptok) * NEXP + eg * 4);
        float nzv[4] = {nz.x, nz.y, nz.z, nz.w};
#pragma unroll
        for (int cc = 0; cc < 4; ++cc) {
            int e = eg * 4 + cc;
            float lg = pw[e * 33 + ptok];
            float nl = pw[(NEXP + e) * 33 + ptok];
            float soft = log1pf(expf(fminf(nl, 20.f)));
            float cmb  = ((nl > 20.f) ? nl : soft) * nzv[cc] + lg;
            if (cmb > v1)      { v2 = v1; i2 = i1; v1 = cmb; i1 = e; }
            else if (cmb > v2) { v2 = cmb; i2 = e; }
        }
        pt[eg * 32 + ptok] = make_float4(v1, (float)i1, v2, (float)i2);
    }
    __syncthreads();

    // merge 16 partials (ascending keeps jax tie-break: lowest index wins)
    if (tid < 32) {
        float4 g = pt[tid];
        float v1 = g.x, v2 = g.z;
        int i1 = (int)g.y, i2 = (int)g.w;
#pragma unroll
        for (int gg = 1; gg < 16; ++gg) {
            float4 p = pt[gg * 32 + tid];
            if (p.x > v1)      { v2 = v1; i2 = i1; v1 = p.x; i1 = (int)p.y; }
            else if (p.x > v2) { v2 = p.x; i2 = (int)p.y; }
            if (p.z > v1)      { v2 = v1; i2 = i1; v1 = p.z; i1 = (int)p.w; }
            else if (p.z > v2) { v2 = p.z; i2 = (int)p.w; }
        }
        float e2  = expf(v2 - v1);
        float inv = 1.f / (1.f + e2);
        fin[tid] = make_float4((float)i1, (float)i2, inv, e2 * inv);
    }
    __syncthreads();

    // probs: thread -> (tok = tid>>4, 4-expert segment tid&15)
    {
        const int tok = tid >> 4;
        const int sg  = tid & 15;
        float4 f = fin[tok];
        int i1 = (int)f.x, i2 = (int)f.y;
        float o[4];
#pragma unroll
        for (int cc = 0; cc < 4; ++cc) {
            int e = sg * 4 + cc;
            o[cc] = (e == i1) ? f.z : ((e == i2) ? f.w : 0.f);
        }
        *(float4*)(out + (size_t)(tok0 + tok) * NEXP + sg * 4) =
            make_float4(o[0], o[1], o[2], o[3]);
    }
    // indices (as float) after the probs region
    if (tid < 32) {
        float4 f = fin[tid];
        *(float2*)(out + (size_t)NTOK * NEXP + (size_t)(tok0 + tid) * 2) = make_float2(f.x, f.y);
    }
#undef LOADX
#undef STAGE
}

extern "C" void kernel_launch(void* const* d_in, const int* in_sizes, int n_in,
                              void* d_out, int out_size, void* d_ws, size_t ws_size,
                              hipStream_t stream) {
    const float* x  = (const float*)d_in[0];
    const float* Wt = (const float*)d_in[1];
    const float* Wn = (const float*)d_in[2];
    const float* nz = (const float*)d_in[3];
    float* out = (float*)d_out;
    _Float16* WB = (_Float16*)d_ws;   // 2 * 262144 halfs = 1 MB scratch

    hipLaunchKernelGGL(pack_w, dim3(128), dim3(256), 0, stream, Wt, Wn, WB);
    hipLaunchKernelGGL(router_main, dim3(NTOK / TOKB), dim3(512), 0, stream, x, WB, nz, out);
}